// Round 7
// baseline (240.633 us; speedup 1.0000x reference)
//
#include <hip/hip_runtime.h>
#include <hip/hip_bf16.h>
#include <math.h>

// Problem constants (B=4, L=1024, D=A=1024, H=16, DH=64)
#define BB 4
#define LL 1024
#define DD 1024
#define AA 1024
#define HH 16
#define DHH 64
#define LOG2E 1.44269504f
#define QSC 0.045084223f        /* (1/32) * log2(e) */
#define MBIAS -144269.5f        /* -100000 * log2(e) */

typedef __attribute__((ext_vector_type(8))) short short8;
typedef __attribute__((ext_vector_type(4))) float floatx4;

__device__ __forceinline__ float bf2f(unsigned short u) {
    union { unsigned u; float f; } x; x.u = ((unsigned)u) << 16; return x.f;
}
__device__ __forceinline__ unsigned short f2bf(float f) {
    union { float f; unsigned u; } x; x.f = f;
    unsigned r = x.u + 0x7fffu + ((x.u >> 16) & 1u); // RNE
    return (unsigned short)(r >> 16);
}
__device__ __forceinline__ unsigned pkbf(float a, float b) { // packed RNE pair
    union { __hip_bfloat162 h; unsigned u; } c;
    c.h = __float22bfloat162_rn(make_float2(a, b));
    return c.u;
}

// async global->LDS, 16B per lane. LDS dest = wave-uniform base + lane*16.
__device__ __forceinline__ void gload16(const void* g, const void* l) {
    __builtin_amdgcn_global_load_lds(
        (const __attribute__((address_space(1))) unsigned int*)g,
        (__attribute__((address_space(3))) unsigned int*)l, 16, 0, 0);
}

// Bijective XCD remap for 512-block (16x32) z-slices (wo kernel).
__device__ __forceinline__ void remap8(int& bx, int& by) {
    const int lin = blockIdx.x + (blockIdx.y << 4);
    const int xcd = lin & 7, f = lin >> 3;          // f in 0..63
    by = ((xcd >> 1) << 3) + (f >> 3);
    bx = ((xcd & 1) << 3) + (f & 7);
}

// Bijective XCD remap for 256-block (8x32) z-slices (proj kernels):
// each XCD gets a 4bx x 8by sub-grid -> unique working set ~2MB A + 2MB W
// fits the 4MB per-XCD L2.
__device__ __forceinline__ void remap128(int& bx, int& by) {
    const int lin = blockIdx.x + (blockIdx.y << 3);
    const int xcd = lin & 7, f = lin >> 3;          // f in 0..31
    bx = ((xcd & 1) << 2) + (f & 3);
    by = ((xcd >> 1) << 3) + (f >> 2);
}

// ---------------------------------------------------------------------------
// fp32 -> bf16 bulk converter. Unit = 1M elems = 1024 blocks; block = 1024 elems.
// ---------------------------------------------------------------------------
struct ConvDesc { const float* s[8]; unsigned short* d[8]; };

__global__ __launch_bounds__(256) void conv_f2b(ConvDesc cd) {
    const int u  = blockIdx.x >> 10;
    const int lb = blockIdx.x & 1023;
    const int idx = lb * 1024 + threadIdx.x * 4;
    float4 v = *reinterpret_cast<const float4*>(cd.s[u] + idx);
    uint2 o;
    o.x = pkbf(v.x, v.y);
    o.y = pkbf(v.z, v.w);
    *reinterpret_cast<uint2*>(cd.d[u] + idx) = o;
}

// ---------------------------------------------------------------------------
// 128x128-tile GEMM pass, BK=64, 2-barrier loop (m97 shape: 64x64 per wave,
// reads/MFMA = 0.5 vs 0.75 at 64x32/wave).
//   A: bf16 via global_load_lds, source-col pre-swizzled (rule #21).
//   B: fp32 weights (128 rows/step), reg-prefetched one step ahead,
//      converted at swizzled ds_write.
// LDS: As[128][64] + Bs[128][64] = 32KB contiguous (S); epilogue reuses S.
// C[m][n] += sum_{k range} A[m][k]*B[n][k].
// ---------------------------------------------------------------------------
__device__ __forceinline__ void gemm_pass128(const unsigned short* A, const float* B,
                                             int mblk, int nblk,
                                             int kbase, int ksteps,
                                             unsigned short* As, unsigned short* Bs,
                                             floatx4 (&acc)[4][4])
{
    const int tid  = threadIdx.x;
    const int lane = tid & 63;
    const int l16  = lane & 15;
    const int quad = lane >> 4;
    const int wave = tid >> 6;
    const int wm = wave >> 1, wn = wave & 1;
    // A staging: issue `is` covers row is*32 + wave*8 + lane/8; source col
    // XOR-pre-swizzled so the linear LDS write lands in swizzled layout.
    const int arow = wave * 8 + (lane >> 3);
    const int acol = ((lane & 7) ^ (lane >> 3)) << 3;
    // B staging: rows tid/8 (+32,+64,+96), source col (tid&7)*8, swizzled slot.
    const int brow = tid >> 3;                    // 0..31
    const int bcol = (tid & 7) << 3;
    const int bslot = ((tid & 7) ^ (brow & 7)) << 3;

    const unsigned short* ap = A + (size_t)(mblk + arow) * DD + kbase + acol;
    const float* bp0 = B + (size_t)(nblk + brow) * DD + kbase + bcol;
    const float* bp1 = bp0 + (size_t)32 * DD;
    const float* bp2 = bp0 + (size_t)64 * DD;
    const float* bp3 = bp0 + (size_t)96 * DD;

    float4 br[8];
    br[0] = ((const float4*)bp0)[0]; br[1] = ((const float4*)bp0)[1];
    br[2] = ((const float4*)bp1)[0]; br[3] = ((const float4*)bp1)[1];
    br[4] = ((const float4*)bp2)[0]; br[5] = ((const float4*)bp2)[1];
    br[6] = ((const float4*)bp3)[0]; br[7] = ((const float4*)bp3)[1];

    for (int s = 0; s < ksteps; ++s) {
        __syncthreads();                      // prev compute done, LDS free
        // async A tile loads (4 issues x 4KB = 128x64 bf16), swizzled source
        for (int is = 0; is < 4; ++is)
            gload16(ap + (size_t)(is * 32) * DD, As + is * 2048 + wave * 512);
        // B: drain prefetched regs -> LDS (convert fp32->bf16), swizzled slot
        {
            uint4 t;
            t.x = pkbf(br[0].x, br[0].y); t.y = pkbf(br[0].z, br[0].w);
            t.z = pkbf(br[1].x, br[1].y); t.w = pkbf(br[1].z, br[1].w);
            *reinterpret_cast<uint4*>(Bs + brow * 64 + bslot) = t;
            t.x = pkbf(br[2].x, br[2].y); t.y = pkbf(br[2].z, br[2].w);
            t.z = pkbf(br[3].x, br[3].y); t.w = pkbf(br[3].z, br[3].w);
            *reinterpret_cast<uint4*>(Bs + (brow + 32) * 64 + bslot) = t;
            t.x = pkbf(br[4].x, br[4].y); t.y = pkbf(br[4].z, br[4].w);
            t.z = pkbf(br[5].x, br[5].y); t.w = pkbf(br[5].z, br[5].w);
            *reinterpret_cast<uint4*>(Bs + (brow + 64) * 64 + bslot) = t;
            t.x = pkbf(br[6].x, br[6].y); t.y = pkbf(br[6].z, br[6].w);
            t.z = pkbf(br[7].x, br[7].y); t.w = pkbf(br[7].z, br[7].w);
            *reinterpret_cast<uint4*>(Bs + (brow + 96) * 64 + bslot) = t;
        }
        __syncthreads();                      // vmcnt+lgkm drain by compiler
        // prefetch next step's B regs (latency spans compute + next barrier)
        if (s + 1 < ksteps) {
            bp0 += 64; bp1 += 64; bp2 += 64; bp3 += 64;
            br[0] = ((const float4*)bp0)[0]; br[1] = ((const float4*)bp0)[1];
            br[2] = ((const float4*)bp1)[0]; br[3] = ((const float4*)bp1)[1];
            br[4] = ((const float4*)bp2)[0]; br[5] = ((const float4*)bp2)[1];
            br[6] = ((const float4*)bp3)[0]; br[7] = ((const float4*)bp3)[1];
        }
        ap += 64;
        // compute: 2 k-halves x (4x4) MFMA, swizzled fragment reads
        for (int kh = 0; kh < 2; ++kh) {
            const int sl = ((kh * 4 + quad) ^ (l16 & 7)) << 3;
            short8 af[4], bfr[4];
            for (int i = 0; i < 4; ++i)
                af[i] = *reinterpret_cast<const short8*>(
                    As + (wm * 64 + i * 16 + l16) * 64 + sl);
            for (int j = 0; j < 4; ++j)
                bfr[j] = *reinterpret_cast<const short8*>(
                    Bs + (wn * 64 + j * 16 + l16) * 64 + sl);
            for (int i = 0; i < 4; ++i)
                for (int j = 0; j < 4; ++j)
                    acc[i][j] = __builtin_amdgcn_mfma_f32_16x16x32_bf16(
                        af[i], bfr[j], acc[i][j], 0, 0, 0);
        }
    }
}

// Epilogue (128x128): per-wave 64x64 transpose in S (8KB/wave), 16B stores.
__device__ __forceinline__ void store_nat128(floatx4 (&acc)[4][4], unsigned short* S,
                                             unsigned short* C, int mblk, int nblk)
{
    const int lane = threadIdx.x & 63;
    const int l16  = lane & 15;
    const int quad = lane >> 4;
    const int wave = threadIdx.x >> 6;
    const int wm = wave >> 1, wn = wave & 1;
    __syncthreads();                              // all waves done reading S
    unsigned short* Cw = S + wave * 4096;         // [64][64] per wave
    for (int i = 0; i < 4; ++i)
        for (int j = 0; j < 4; ++j)
            for (int r = 0; r < 4; ++r)
                Cw[(i * 16 + quad * 4 + r) * 64 + j * 16 + l16] = f2bf(acc[i][j][r]);
    __asm__ volatile("s_waitcnt lgkmcnt(0)" ::: "memory");
    const int mb = mblk + wm * 64;
    const int nb = nblk + wn * 64;
    for (int s = 0; s < 8; ++s) {
        const int row = s * 8 + (lane >> 3);
        uint4 v = *reinterpret_cast<const uint4*>(Cw + row * 64 + (lane & 7) * 8);
        *reinterpret_cast<uint4*>(C + (size_t)(mb + row) * AA + nb + (lane & 7) * 8) = v;
    }
}

// V^T epilogue (128x128): wave covers one full head (64 dh) x 64 l.
// vt[((b*H+h)*DH+dh)*L + l]; h = nblk/64 + wn.
__device__ __forceinline__ void store_vt128(floatx4 (&acc)[4][4], unsigned short* S,
                                            unsigned short* vt, int mblk, int nblk)
{
    const int lane = threadIdx.x & 63;
    const int l16  = lane & 15;
    const int quad = lane >> 4;
    const int wave = threadIdx.x >> 6;
    const int wm = wave >> 1, wn = wave & 1;
    __syncthreads();
    unsigned short* Cw = S + wave * 4096;         // [64 dh][64 l] per wave
    for (int i = 0; i < 4; ++i)
        for (int j = 0; j < 4; ++j) {
            ushort4 pv;
            pv.x = f2bf(acc[i][j][0]); pv.y = f2bf(acc[i][j][1]);
            pv.z = f2bf(acc[i][j][2]); pv.w = f2bf(acc[i][j][3]);
            *reinterpret_cast<ushort4*>(&Cw[(j * 16 + l16) * 64 + i * 16 + quad * 4]) = pv;
        }
    __asm__ volatile("s_waitcnt lgkmcnt(0)" ::: "memory");
    const int mg = mblk + wm * 64;
    const int b  = mg >> 10, lbase = mg & 1023;
    const int h  = (nblk >> 6) + wn;
    for (int s = 0; s < 8; ++s) {
        const int drow = s * 8 + (lane >> 3);     // 0..63 dh
        uint4 v = *reinterpret_cast<const uint4*>(Cw + drow * 64 + (lane & 7) * 8);
        *reinterpret_cast<uint4*>(
            vt + (size_t)((b * HH + h) * DHH + drow) * LL + lbase + (lane & 7) * 8) = v;
    }
}

// Fully fused q/k/v projections (requires vt not aliasing qb).
// grid (8, 32, 3): z=0 q (two passes), z=1 k, z=2 v. 768 blocks -> 3/CU.
__global__ __launch_bounds__(256, 3) void gemm_proj3(
    const unsigned short* __restrict__ xb, const unsigned short* __restrict__ qb,
    const float* __restrict__ Wqs, const float* __restrict__ Wqo,
    const float* __restrict__ Wk, const float* __restrict__ Wv,
    unsigned short* __restrict__ qc, unsigned short* __restrict__ kk,
    unsigned short* __restrict__ vt)
{
    __shared__ alignas(16) unsigned short S[128 * 64 * 2];
    unsigned short* As = S;
    unsigned short* Bs = S + 128 * 64;
    floatx4 acc[4][4] = {};
    int bx, by; remap128(bx, by);
    const int mblk = by * 128, nblk = bx * 128;
    if (blockIdx.z == 0) {
        gemm_pass128(xb, Wqs, mblk, nblk, 0, 16, As, Bs, acc);
        gemm_pass128(qb, Wqo, mblk, nblk, 0, 16, As, Bs, acc);
        store_nat128(acc, S, qc, mblk, nblk);
    } else if (blockIdx.z == 1) {
        gemm_pass128(xb, Wk, mblk, nblk, 0, 16, As, Bs, acc);
        store_nat128(acc, S, kk, mblk, nblk);
    } else {
        gemm_pass128(xb, Wv, mblk, nblk, 0, 16, As, Bs, acc);
        store_vt128(acc, S, vt, mblk, nblk);
    }
}

// Lean path (vt aliases qb): q+k fused first, v alone after q consumed qb.
__global__ __launch_bounds__(256, 3) void gemm_projqk(
    const unsigned short* __restrict__ xb, const unsigned short* __restrict__ qb,
    const float* __restrict__ Wqs, const float* __restrict__ Wqo,
    const float* __restrict__ Wk,
    unsigned short* __restrict__ qc, unsigned short* __restrict__ kk)
{
    __shared__ alignas(16) unsigned short S[128 * 64 * 2];
    unsigned short* As = S;
    unsigned short* Bs = S + 128 * 64;
    floatx4 acc[4][4] = {};
    int bx, by; remap128(bx, by);
    const int mblk = by * 128, nblk = bx * 128;
    if (blockIdx.z == 0) {
        gemm_pass128(xb, Wqs, mblk, nblk, 0, 16, As, Bs, acc);
        gemm_pass128(qb, Wqo, mblk, nblk, 0, 16, As, Bs, acc);
        store_nat128(acc, S, qc, mblk, nblk);
    } else {
        gemm_pass128(xb, Wk, mblk, nblk, 0, 16, As, Bs, acc);
        store_nat128(acc, S, kk, mblk, nblk);
    }
}

__global__ __launch_bounds__(256, 3) void gemm_v(
    const unsigned short* __restrict__ xb, const float* __restrict__ Wv,
    unsigned short* __restrict__ vt)
{
    __shared__ alignas(16) unsigned short S[128 * 64 * 2];
    unsigned short* As = S;
    unsigned short* Bs = S + 128 * 64;
    floatx4 acc[4][4] = {};
    int bx, by; remap128(bx, by);
    gemm_pass128(xb, Wv, by * 128, bx * 128, 0, 16, As, Bs, acc);
    store_vt128(acc, S, vt, by * 128, bx * 128);
}

// ---------------------------------------------------------------------------
// Old 128x64-tile pass (kept for the Wo GEMM: split-K needs the 1024-block
// grid for TLP; serves as an in-flight control vs the 128x128 core).
// ---------------------------------------------------------------------------
__device__ __forceinline__ void gemm_pass(const unsigned short* A, const float* B,
                                          int mblk, int nblk,
                                          int kbase, int ksteps,
                                          unsigned short* As, unsigned short* Bs,
                                          floatx4 (&acc)[4][2])
{
    const int tid  = threadIdx.x;
    const int lane = tid & 63;
    const int l16  = lane & 15;
    const int quad = lane >> 4;
    const int wave = tid >> 6;
    const int wm = wave >> 1, wn = wave & 1;
    const int arow = wave * 8 + (lane >> 3);
    const int acol = ((lane & 7) ^ (lane >> 3)) << 3;
    const int brow = tid >> 3;
    const int bcol = (tid & 7) << 3;
    const int bslot = ((tid & 7) ^ (brow & 7)) << 3;

    float4 br[4];
    {
        const float* p0 = B + (size_t)(nblk + brow) * DD + kbase + bcol;
        const float* p1 = B + (size_t)(nblk + brow + 32) * DD + kbase + bcol;
        br[0] = ((const float4*)p0)[0]; br[1] = ((const float4*)p0)[1];
        br[2] = ((const float4*)p1)[0]; br[3] = ((const float4*)p1)[1];
    }

    for (int s = 0; s < ksteps; ++s) {
        const int k0 = kbase + s * 64;
        __syncthreads();
        for (int is = 0; is < 4; ++is)
            gload16(A + (size_t)(mblk + is * 32 + arow) * DD + k0 + acol,
                    As + is * 2048 + wave * 512);
        {
            uint4 t0, t1;
            t0.x = pkbf(br[0].x, br[0].y); t0.y = pkbf(br[0].z, br[0].w);
            t0.z = pkbf(br[1].x, br[1].y); t0.w = pkbf(br[1].z, br[1].w);
            t1.x = pkbf(br[2].x, br[2].y); t1.y = pkbf(br[2].z, br[2].w);
            t1.z = pkbf(br[3].x, br[3].y); t1.w = pkbf(br[3].z, br[3].w);
            *reinterpret_cast<uint4*>(Bs + brow * 64 + bslot) = t0;
            *reinterpret_cast<uint4*>(Bs + (brow + 32) * 64 + bslot) = t1;
        }
        __syncthreads();
        if (s + 1 < ksteps) {
            const int nk = k0 + 64;
            const float* p0 = B + (size_t)(nblk + brow) * DD + nk + bcol;
            const float* p1 = B + (size_t)(nblk + brow + 32) * DD + nk + bcol;
            br[0] = ((const float4*)p0)[0]; br[1] = ((const float4*)p0)[1];
            br[2] = ((const float4*)p1)[0]; br[3] = ((const float4*)p1)[1];
        }
        for (int kh = 0; kh < 2; ++kh) {
            const int sl = ((kh * 4 + quad) ^ (l16 & 7)) << 3;
            short8 af[4], bfr[2];
            for (int i = 0; i < 4; ++i)
                af[i] = *reinterpret_cast<const short8*>(
                    As + (wm * 64 + i * 16 + l16) * 64 + sl);
            for (int j = 0; j < 2; ++j)
                bfr[j] = *reinterpret_cast<const short8*>(
                    Bs + (wn * 32 + j * 16 + l16) * 64 + sl);
            for (int i = 0; i < 4; ++i)
                for (int j = 0; j < 2; ++j)
                    acc[i][j] = __builtin_amdgcn_mfma_f32_16x16x32_bf16(
                        af[i], bfr[j], acc[i][j], 0, 0, 0);
        }
    }
}

__device__ __forceinline__ void store_nat(floatx4 (&acc)[4][2], unsigned short* As,
                                          unsigned short* C, int mblk, int nblk)
{
    const int lane = threadIdx.x & 63;
    const int l16  = lane & 15;
    const int quad = lane >> 4;
    const int wave = threadIdx.x >> 6;
    const int wm = wave >> 1, wn = wave & 1;
    __syncthreads();
    unsigned short* Cw = As + wave * 2048;        // [64][32] per wave
    for (int i = 0; i < 4; ++i)
        for (int j = 0; j < 2; ++j)
            for (int r = 0; r < 4; ++r)
                Cw[(i * 16 + quad * 4 + r) * 32 + j * 16 + l16] = f2bf(acc[i][j][r]);
    __asm__ volatile("s_waitcnt lgkmcnt(0)" ::: "memory");
    const int mb = mblk + wm * 64;
    const int nb = nblk + wn * 32;
    for (int s = 0; s < 4; ++s) {
        const int row = s * 16 + (lane >> 2);
        uint4 v = *reinterpret_cast<const uint4*>(Cw + row * 32 + (lane & 3) * 8);
        *reinterpret_cast<uint4*>(C + (size_t)(mb + row) * AA + nb + (lane & 3) * 8) = v;
    }
}

// Wo projection, split-K x2: z = K-half, bf16 partials to pj0/pj1 (summed in ln).
// grid (16, 32, 2) = 1024 blocks -> 4/CU.
__global__ __launch_bounds__(256) void gemm_wo(
    const unsigned short* __restrict__ ao, const float* __restrict__ Wo,
    unsigned short* __restrict__ pj0, unsigned short* __restrict__ pj1)
{
    __shared__ alignas(16) unsigned short As[128 * 64];
    __shared__ alignas(16) unsigned short Bs[64 * 64];
    floatx4 acc[4][2] = {};
    int bx, by; remap8(bx, by);
    const int z = blockIdx.z;
    gemm_pass(ao, Wo, by * 128, bx * 64, z * 512, 8, As, Bs, acc);
    store_nat(acc, As, z ? pj1 : pj0, by * 128, bx * 64);
}

// ---------------------------------------------------------------------------
// Flash attention, swapped-QK^T in-register softmax (no online max: scores
// bounded, masked cols underflow to 0 via MBIAS in the C-init add).
// mfma(K,Q) makes the P-row lane-local -> P->bf16 via cvt_pk + 16 shfl
// (no Plds round-trip, no lgkmcnt(0) stop). K/V double-buffered in LDS with
// ONE barrier per iteration; staging writes overlap compute; loads 2 tiles
// deep. LDS 36KB -> 4 blocks/CU.
// ---------------------------------------------------------------------------
__device__ __forceinline__ int swzb(int row, int slot) {
    // byte offset into a 64-row x 128B tile, slot = 16B column, XOR-swizzled
    return (row << 7) + ((slot ^ (row & 7)) << 4);
}

__global__ __launch_bounds__(256, 4) void attn_flash(const unsigned short* qc,
                                                     const unsigned short* __restrict__ kmat,
                                                     const unsigned short* __restrict__ vt,
                                                     const int* __restrict__ mask,
                                                     unsigned short* ao)
{
    const int blk = blockIdx.x;
    const int xcd = blk & 7;
    const int sub = blk >> 3;          // 0..127
    const int bh  = xcd * 8 + (sub >> 4);
    const int qt  = sub & 15;
    const int b   = bh >> 4;
    const int h   = bh & 15;

    const int wave = threadIdx.x >> 6;
    const int lane = threadIdx.x & 63;
    const int l16  = lane & 15;
    const int quad = lane >> 4;
    const int q0 = qt * 64 + wave * 16;

    __shared__ alignas(16) unsigned short Ks[2][64 * 64]; // swizzled [k][dh] 16KB
    __shared__ alignas(16) unsigned short Vs[2][64 * 64]; // swizzled [dh][k] 16KB
    __shared__ float Ml[LL];                              // mask bias         4KB

    const int* bm = mask + b * LL;
    for (int i = 0; i < 4; ++i) {
        const int c = threadIdx.x + i * 256;
        Ml[c] = (1.0f - (float)bm[c]) * MBIAS;
    }

    short8 aq[2];
    for (int s = 0; s < 2; ++s) {
        const unsigned short* p =
            qc + (size_t)(b * LL + q0 + l16) * AA + h * DHH + s * 32 + quad * 8;
        short8 t = *reinterpret_cast<const short8*>(p);
        for (int e = 0; e < 8; ++e)
            t[e] = (short)f2bf(bf2f((unsigned short)t[e]) * QSC);
        aq[s] = t;
    }

    floatx4 O[4] = {};
    float lp = 0.f;

    const unsigned short* kbase = kmat + (size_t)(b * LL) * AA + h * DHH;
    const unsigned short* vbase = vt + (size_t)((b * HH + h) * DHH) * LL;
    const int c0 = threadIdx.x, c1 = threadIdx.x + 256;
    const int row0 = c0 >> 3, slot0 = c0 & 7;   // rows 0..31
    const int row1 = c1 >> 3, slot1 = c1 & 7;   // rows 32..63

    uint4 kr0, kr1, vr0, vr1;
    kr0 = *reinterpret_cast<const uint4*>(kbase + (size_t)row0 * AA + slot0 * 8);
    kr1 = *reinterpret_cast<const uint4*>(kbase + (size_t)row1 * AA + slot1 * 8);
    vr0 = *reinterpret_cast<const uint4*>(vbase + (size_t)row0 * LL + slot0 * 8);
    vr1 = *reinterpret_cast<const uint4*>(vbase + (size_t)row1 * LL + slot1 * 8);
    *reinterpret_cast<uint4*>((char*)Ks[0] + swzb(row0, slot0)) = kr0;
    *reinterpret_cast<uint4*>((char*)Ks[0] + swzb(row1, slot1)) = kr1;
    *reinterpret_cast<uint4*>((char*)Vs[0] + swzb(row0, slot0)) = vr0;
    *reinterpret_cast<uint4*>((char*)Vs[0] + swzb(row1, slot1)) = vr1;
    {
        const unsigned short* kb1 = kbase + (size_t)64 * AA;
        const unsigned short* vb1 = vbase + 64;
        kr0 = *reinterpret_cast<const uint4*>(kb1 + (size_t)row0 * AA + slot0 * 8);
        kr1 = *reinterpret_cast<const uint4*>(kb1 + (size_t)row1 * AA + slot1 * 8);
        vr0 = *reinterpret_cast<const uint4*>(vb1 + (size_t)row0 * LL + slot0 * 8);
        vr1 = *reinterpret_cast<const uint4*>(vb1 + (size_t)row1 * LL + slot1 * 8);
    }
    __syncthreads();

    const int srcA = ((quad & 1) << 5) + l16;   // source lanes for P redistribute
    const int srcB = srcA + 16;
    const bool hi = quad >= 2;                  // target j = quad>>1 selector
    int cur = 0;

    for (int t = 0; t < 16; ++t) {
        const char* Kc = (const char*)Ks[cur];
        const char* Vc = (const char*)Vs[cur];
        if (t + 1 < 16) {
            char* Kn = (char*)Ks[cur ^ 1];
            char* Vn = (char*)Vs[cur ^ 1];
            *reinterpret_cast<uint4*>(Kn + swzb(row0, slot0)) = kr0;
            *reinterpret_cast<uint4*>(Kn + swzb(row1, slot1)) = kr1;
            *reinterpret_cast<uint4*>(Vn + swzb(row0, slot0)) = vr0;
            *reinterpret_cast<uint4*>(Vn + swzb(row1, slot1)) = vr1;
        }
        if (t + 2 < 16) {
            const unsigned short* kb2 = kbase + (size_t)(t + 2) * 64 * AA;
            const unsigned short* vb2 = vbase + (t + 2) * 64;
            kr0 = *reinterpret_cast<const uint4*>(kb2 + (size_t)row0 * AA + slot0 * 8);
            kr1 = *reinterpret_cast<const uint4*>(kb2 + (size_t)row1 * AA + slot1 * 8);
            vr0 = *reinterpret_cast<const uint4*>(vb2 + (size_t)row0 * LL + slot0 * 8);
            vr1 = *reinterpret_cast<const uint4*>(vb2 + (size_t)row1 * LL + slot1 * 8);
        }

        floatx4 p[4];
        const float* Mlb = Ml + t * 64 + quad * 4;
        for (int j = 0; j < 4; ++j) {
            const int rr = j * 16 + l16;
            const short8 kf0 = *reinterpret_cast<const short8*>(Kc + swzb(rr, quad));
            const short8 kf1 = *reinterpret_cast<const short8*>(Kc + swzb(rr, quad + 4));
            floatx4 s_ = {0.f, 0.f, 0.f, 0.f};
            s_ = __builtin_amdgcn_mfma_f32_16x16x32_bf16(kf0, aq[0], s_, 0, 0, 0);
            s_ = __builtin_amdgcn_mfma_f32_16x16x32_bf16(kf1, aq[1], s_, 0, 0, 0);
            const float4 mv = *reinterpret_cast<const float4*>(Mlb + j * 16);
            p[j][0] = exp2f(s_[0] + mv.x);
            p[j][1] = exp2f(s_[1] + mv.y);
            p[j][2] = exp2f(s_[2] + mv.z);
            p[j][3] = exp2f(s_[3] + mv.w);
            lp += (p[j][0] + p[j][1]) + (p[j][2] + p[j][3]);
        }
        unsigned pk[4][2];
        for (int j = 0; j < 4; ++j) {
            pk[j][0] = pkbf(p[j][0], p[j][1]);
            pk[j][1] = pkbf(p[j][2], p[j][3]);
        }
        union { unsigned u[4]; short8 s; } ap0, ap1;
        {
            unsigned xA0 = __shfl((int)pk[0][0], srcA), yA0 = __shfl((int)pk[1][0], srcA);
            unsigned xA1 = __shfl((int)pk[0][1], srcA), yA1 = __shfl((int)pk[1][1], srcA);
            unsigned xB0 = __shfl((int)pk[0][0], srcB), yB0 = __shfl((int)pk[1][0], srcB);
            unsigned xB1 = __shfl((int)pk[0][1], srcB), yB1 = __shfl((int)pk[1][1], srcB);
            ap0.u[0] = hi ? yA0 : xA0;
            ap0.u[1] = hi ? yA1 : xA1;
            ap0.u[2] = hi ? yB0 : xB0;
            ap0.u[3] = hi ? yB1 : xB1;
        }
        {
            unsigned xA0 = __shfl((int)pk[2][0], srcA), yA0 = __shfl((int)pk[3][0], srcA);
            unsigned xA1 = __shfl((int)pk[2][1], srcA), yA1 = __shfl((int)pk[3][1], srcA);
            unsigned xB0 = __shfl((int)pk[2][0], srcB), yB0 = __shfl((int)pk[3][0], srcB);
            unsigned xB1 = __shfl((int)pk[2][1], srcB), yB1 = __shfl((int)pk[3][1], srcB);
            ap1.u[0] = hi ? yA0 : xA0;
            ap1.u[1] = hi ? yA1 : xA1;
            ap1.u[2] = hi ? yB0 : xB0;
            ap1.u[3] = hi ? yB1 : xB1;
        }
        for (int t4 = 0; t4 < 4; ++t4) {
            const int rr = t4 * 16 + l16;
            const short8 bv0 = *reinterpret_cast<const short8*>(Vc + swzb(rr, quad));
            const short8 bv1 = *reinterpret_cast<const short8*>(Vc + swzb(rr, quad + 4));
            O[t4] = __builtin_amdgcn_mfma_f32_16x16x32_bf16(ap0.s, bv0, O[t4], 0, 0, 0);
            O[t4] = __builtin_amdgcn_mfma_f32_16x16x32_bf16(ap1.s, bv1, O[t4], 0, 0, 0);
        }
        __syncthreads();
        cur ^= 1;
    }

    lp += __shfl_xor(lp, 16);
    lp += __shfl_xor(lp, 32);
    float linv[4];
    for (int r = 0; r < 4; ++r) {
        const float s = __shfl(lp, quad * 4 + r);
        linv[r] = 1.0f / s;
    }
    for (int t4 = 0; t4 < 4; ++t4)
        for (int r = 0; r < 4; ++r)
            ao[(size_t)(b * LL + q0 + quad * 4 + r) * AA + h * DHH + t4 * 16 + l16] =
                f2bf(O[t4][r] * linv[r]);
}

// bias + LayerNorm per 1024-row. Sums two bf16 partials; params fp32; out FP32.
__global__ __launch_bounds__(256) void ln_f32(const unsigned short* __restrict__ X0,
                                              const unsigned short* __restrict__ X1,
                                              const float* __restrict__ bo,
                                              const float* __restrict__ gamma,
                                              const float* __restrict__ beta,
                                              float* __restrict__ out)
{
    const int row = blockIdx.x;
    const unsigned short* x0 = X0 + (size_t)row * AA;
    const unsigned short* x1 = X1 + (size_t)row * AA;
    float v[4];
    float s = 0.f, s2 = 0.f;
    for (int e = 0; e < 4; ++e) {
        const int c = threadIdx.x + e * 256;
        const float f = bf2f(x0[c]) + bf2f(x1[c]) + bo[c];
        v[e] = f; s += f; s2 += f * f;
    }
    for (int d = 1; d < 64; d <<= 1) { s += __shfl_xor(s, d); s2 += __shfl_xor(s2, d); }
    __shared__ float red[4][2];
    const int wave = threadIdx.x >> 6;
    const int lane = threadIdx.x & 63;
    if (lane == 0) { red[wave][0] = s; red[wave][1] = s2; }
    __syncthreads();
    s  = red[0][0] + red[1][0] + red[2][0] + red[3][0];
    s2 = red[0][1] + red[1][1] + red[2][1] + red[3][1];
    const float mean = s * (1.0f / AA);
    const float var  = s2 * (1.0f / AA) - mean * mean;
    const float rstd = rsqrtf(var + 1e-5f);
    for (int e = 0; e < 4; ++e) {
        const int c = threadIdx.x + e * 256;
        out[(size_t)row * AA + c] = (v[e] - mean) * rstd * gamma[c] + beta[c];
    }
}

extern "C" void kernel_launch(void* const* d_in, const int* in_sizes, int n_in,
                              void* d_out, int out_size, void* d_ws, size_t ws_size,
                              hipStream_t stream)
{
    const float* x     = (const float*)d_in[0];  // fp32 [B][L][D]
    const float* qrs   = (const float*)d_in[1];
    const float* Wk    = (const float*)d_in[2];  // fp32 [A][D]
    const float* Wqs   = (const float*)d_in[3];
    const float* Wqo   = (const float*)d_in[4];
    const float* Wv    = (const float*)d_in[5];
    const float* Wo    = (const float*)d_in[6];
    const float* bo    = (const float*)d_in[7];
    const float* gamma = (const float*)d_in[8];
    const float* beta  = (const float*)d_in[9];
    const int*   mask  = (const int*)d_in[10];

    // Scratch plan (weights stay fp32, B-side reg-converted):
    //   ws[0,8):    xb (dead after projections) -> then pj0 (Wo K-half 0)
    //   ws[8,16):   qb (dead after q-pass)      -> then vt (lean path)
    //   ws[16,24):  vt (big path, ws >= 24 MiB) -> full q/k/v fusion possible
    //   d_out[0,8): qc (attn overwrites own region with ao)
    //   d_out[8,16): kk (dead after attn)       -> then pj1 (Wo K-half 1)
    //   d_out[0,16): final fp32 (written last by ln)
    char* ws = (char*)d_ws;
    unsigned short* xb = (unsigned short*)(ws + (size_t)0);
    unsigned short* qb = (unsigned short*)(ws + ((size_t)8 << 20));
    const bool big = ws_size >= ((size_t)24 << 20);
    unsigned short* vt = big ? (unsigned short*)(ws + ((size_t)16 << 20)) : qb;
    unsigned short* qc = (unsigned short*)d_out;
    unsigned short* kk = (unsigned short*)((char*)d_out + ((size_t)8 << 20));
    unsigned short* ao  = qc;
    unsigned short* pj0 = xb;
    unsigned short* pj1 = kk;

    ConvDesc cd;
    for (int i = 0; i < 4; ++i) {
        cd.s[i]     = x   + (size_t)i * (1u << 20); cd.d[i]     = xb + (size_t)i * (1u << 20);
        cd.s[i + 4] = qrs + (size_t)i * (1u << 20); cd.d[i + 4] = qb + (size_t)i * (1u << 20);
    }
    conv_f2b<<<8 * 1024, 256, 0, stream>>>(cd);

    if (big) {
        dim3 g3(AA / 128, (BB * LL) / 128, 3);
        gemm_proj3<<<g3, 256, 0, stream>>>(xb, qb, Wqs, Wqo, Wk, Wv, qc, kk, vt);
    } else {
        dim3 g2(AA / 128, (BB * LL) / 128, 2);
        dim3 g1(AA / 128, (BB * LL) / 128);
        gemm_projqk<<<g2, 256, 0, stream>>>(xb, qb, Wqs, Wqo, Wk, qc, kk);
        gemm_v<<<g1, 256, 0, stream>>>(xb, Wv, vt);
    }
    attn_flash<<<BB * HH * (LL / 64), 256, 0, stream>>>(qc, kk, vt, mask, ao);
    dim3 gw(AA / 64, (BB * LL) / 128, 2);
    gemm_wo<<<gw, 256, 0, stream>>>(ao, Wo, pj0, pj1);
    ln_f32<<<BB * LL, 256, 0, stream>>>(pj0, pj1, bo, gamma, beta, (float*)d_out);
}

// Round 8
// 235.139 us; speedup vs baseline: 1.0234x; 1.0234x over previous
//
#include <hip/hip_runtime.h>
#include <hip/hip_bf16.h>
#include <math.h>

// Problem constants (B=4, L=1024, D=A=1024, H=16, DH=64)
#define BB 4
#define LL 1024
#define DD 1024
#define AA 1024
#define HH 16
#define DHH 64
#define LOG2E 1.44269504f
#define QSC 0.045084223f        /* (1/32) * log2(e) */
#define MBIAS -144269.5f        /* -100000 * log2(e) */

typedef __attribute__((ext_vector_type(8))) short short8;
typedef __attribute__((ext_vector_type(4))) float floatx4;

__device__ __forceinline__ float bf2f(unsigned short u) {
    union { unsigned u; float f; } x; x.u = ((unsigned)u) << 16; return x.f;
}
__device__ __forceinline__ unsigned short f2bf(float f) {
    union { float f; unsigned u; } x; x.f = f;
    unsigned r = x.u + 0x7fffu + ((x.u >> 16) & 1u); // RNE
    return (unsigned short)(r >> 16);
}
__device__ __forceinline__ unsigned pkbf(float a, float b) { // packed RNE pair
    union { __hip_bfloat162 h; unsigned u; } c;
    c.h = __float22bfloat162_rn(make_float2(a, b));
    return c.u;
}

// async global->LDS, 16B per lane. LDS dest = wave-uniform base + lane*16.
__device__ __forceinline__ void gload16(const void* g, const void* l) {
    __builtin_amdgcn_global_load_lds(
        (const __attribute__((address_space(1))) unsigned int*)g,
        (__attribute__((address_space(3))) unsigned int*)l, 16, 0, 0);
}

// Bijective XCD remap for 512-block (16x32) z-slices: lin&7 = XCD under
// round-robin dispatch; each XCD gets an 8y x 8x sub-grid so its unique
// working set (2MB A-slab + 2MB W-cols) fits the 4MB per-XCD L2.
// (512 % 8 == 0 so each z-slice keeps XCD phase alignment.)
__device__ __forceinline__ void remap8(int& bx, int& by) {
    const int lin = blockIdx.x + (blockIdx.y << 4);
    const int xcd = lin & 7, f = lin >> 3;          // f in 0..63
    by = ((xcd >> 1) << 3) + (f >> 3);
    bx = ((xcd & 1) << 3) + (f & 7);
}

// ---------------------------------------------------------------------------
// fp32 -> bf16 bulk converter. Unit = 1M elems = 1024 blocks; block = 1024 elems.
// ---------------------------------------------------------------------------
struct ConvDesc { const float* s[8]; unsigned short* d[8]; };

__global__ __launch_bounds__(256) void conv_f2b(ConvDesc cd) {
    const int u  = blockIdx.x >> 10;
    const int lb = blockIdx.x & 1023;
    const int idx = lb * 1024 + threadIdx.x * 4;
    float4 v = *reinterpret_cast<const float4*>(cd.s[u] + idx);
    uint2 o;
    o.x = pkbf(v.x, v.y);
    o.y = pkbf(v.z, v.w);
    *reinterpret_cast<uint2*>(cd.d[u] + idx) = o;
}

// ---------------------------------------------------------------------------
// 128x64-tile GEMM pass, BK=64, 2-barrier loop (round-6 proven core: at this
// structure 6 blocks/CU TLP beats fatter tiles — r7 A/B: 128x128@3/CU lost).
//   A: bf16 via global_load_lds, source-col pre-swizzled (rule #21).
//   B: fp32 weights, reg-prefetched one step ahead, swizzled ds_write.
// Fragment reads: slot' = (kh*4+quad) ^ (row&7) -> conflict-free.
// 4 waves (2x2): wave computes 64x32 = 4x2 frags of 16x16.
// C[m][n] += sum_{k range} A[m][k]*B[n][k].
// ---------------------------------------------------------------------------
__device__ __forceinline__ void gemm_pass(const unsigned short* A, const float* B,
                                          int mblk, int nblk,
                                          int kbase, int ksteps,
                                          unsigned short* As, unsigned short* Bs,
                                          floatx4 (&acc)[4][2])
{
    const int tid  = threadIdx.x;
    const int lane = tid & 63;
    const int l16  = lane & 15;
    const int quad = lane >> 4;
    const int wave = tid >> 6;
    const int wm = wave >> 1, wn = wave & 1;
    const int arow = wave * 8 + (lane >> 3);
    const int acol = ((lane & 7) ^ (lane >> 3)) << 3;
    const int brow = tid >> 3;
    const int bcol = (tid & 7) << 3;
    const int bslot = ((tid & 7) ^ (brow & 7)) << 3;

    float4 br[4];
    {   // preload B step 0
        const float* p0 = B + (size_t)(nblk + brow) * DD + kbase + bcol;
        const float* p1 = B + (size_t)(nblk + brow + 32) * DD + kbase + bcol;
        br[0] = ((const float4*)p0)[0]; br[1] = ((const float4*)p0)[1];
        br[2] = ((const float4*)p1)[0]; br[3] = ((const float4*)p1)[1];
    }

    for (int s = 0; s < ksteps; ++s) {
        const int k0 = kbase + s * 64;
        __syncthreads();                      // prev compute done, LDS free
        for (int is = 0; is < 4; ++is)
            gload16(A + (size_t)(mblk + is * 32 + arow) * DD + k0 + acol,
                    As + is * 2048 + wave * 512);
        {
            uint4 t0, t1;
            t0.x = pkbf(br[0].x, br[0].y); t0.y = pkbf(br[0].z, br[0].w);
            t0.z = pkbf(br[1].x, br[1].y); t0.w = pkbf(br[1].z, br[1].w);
            t1.x = pkbf(br[2].x, br[2].y); t1.y = pkbf(br[2].z, br[2].w);
            t1.z = pkbf(br[3].x, br[3].y); t1.w = pkbf(br[3].z, br[3].w);
            *reinterpret_cast<uint4*>(Bs + brow * 64 + bslot) = t0;
            *reinterpret_cast<uint4*>(Bs + (brow + 32) * 64 + bslot) = t1;
        }
        __syncthreads();                      // vmcnt+lgkm drain by compiler
        if (s + 1 < ksteps) {
            const int nk = k0 + 64;
            const float* p0 = B + (size_t)(nblk + brow) * DD + nk + bcol;
            const float* p1 = B + (size_t)(nblk + brow + 32) * DD + nk + bcol;
            br[0] = ((const float4*)p0)[0]; br[1] = ((const float4*)p0)[1];
            br[2] = ((const float4*)p1)[0]; br[3] = ((const float4*)p1)[1];
        }
        for (int kh = 0; kh < 2; ++kh) {
            const int sl = ((kh * 4 + quad) ^ (l16 & 7)) << 3;
            short8 af[4], bfr[2];
            for (int i = 0; i < 4; ++i)
                af[i] = *reinterpret_cast<const short8*>(
                    As + (wm * 64 + i * 16 + l16) * 64 + sl);
            for (int j = 0; j < 2; ++j)
                bfr[j] = *reinterpret_cast<const short8*>(
                    Bs + (wn * 32 + j * 16 + l16) * 64 + sl);
            for (int i = 0; i < 4; ++i)
                for (int j = 0; j < 2; ++j)
                    acc[i][j] = __builtin_amdgcn_mfma_f32_16x16x32_bf16(
                        af[i], bfr[j], acc[i][j], 0, 0, 0);
        }
    }
}

// Epilogue: acc -> per-wave LDS transpose -> full-line 16B coalesced stores.
__device__ __forceinline__ void store_nat(floatx4 (&acc)[4][2], unsigned short* As,
                                          unsigned short* C, int mblk, int nblk)
{
    const int lane = threadIdx.x & 63;
    const int l16  = lane & 15;
    const int quad = lane >> 4;
    const int wave = threadIdx.x >> 6;
    const int wm = wave >> 1, wn = wave & 1;
    __syncthreads();
    unsigned short* Cw = As + wave * 2048;        // [64][32] per wave
    for (int i = 0; i < 4; ++i)
        for (int j = 0; j < 2; ++j)
            for (int r = 0; r < 4; ++r)
                Cw[(i * 16 + quad * 4 + r) * 32 + j * 16 + l16] = f2bf(acc[i][j][r]);
    __asm__ volatile("s_waitcnt lgkmcnt(0)" ::: "memory");
    const int mb = mblk + wm * 64;
    const int nb = nblk + wn * 32;
    for (int s = 0; s < 4; ++s) {
        const int row = s * 16 + (lane >> 2);
        uint4 v = *reinterpret_cast<const uint4*>(Cw + row * 32 + (lane & 3) * 8);
        *reinterpret_cast<uint4*>(C + (size_t)(mb + row) * AA + nb + (lane & 3) * 8) = v;
    }
}

// V^T layout: vt[((b*H+h)*DH+dh)*L + l], wave region 32 dh x 64 l.
__device__ __forceinline__ void store_vt(floatx4 (&acc)[4][2], unsigned short* As,
                                         unsigned short* vt, int mblk, int h)
{
    const int lane = threadIdx.x & 63;
    const int l16  = lane & 15;
    const int quad = lane >> 4;
    const int wave = threadIdx.x >> 6;
    const int wm = wave >> 1, wn = wave & 1;
    __syncthreads();
    unsigned short* Cw = As + wave * 2048;        // [32 dh][64 l] per wave
    for (int i = 0; i < 4; ++i)
        for (int j = 0; j < 2; ++j) {
            ushort4 pv;
            pv.x = f2bf(acc[i][j][0]); pv.y = f2bf(acc[i][j][1]);
            pv.z = f2bf(acc[i][j][2]); pv.w = f2bf(acc[i][j][3]);
            *reinterpret_cast<ushort4*>(&Cw[(j * 16 + l16) * 64 + i * 16 + quad * 4]) = pv;
        }
    __asm__ volatile("s_waitcnt lgkmcnt(0)" ::: "memory");
    const int mg = mblk + wm * 64;
    const int b  = mg >> 10, lbase = mg & 1023;
    for (int s = 0; s < 4; ++s) {
        const int drow = s * 8 + (lane >> 3);     // 0..31
        uint4 v = *reinterpret_cast<const uint4*>(Cw + drow * 64 + (lane & 7) * 8);
        *reinterpret_cast<uint4*>(
            vt + (size_t)((b * HH + h) * DHH + wn * 32 + drow) * LL + lbase + (lane & 7) * 8) = v;
    }
}

// Balanced 4-slice projections (needs qo buffer: ws >= 32 MiB).
// grid (16, 32, 4): z=0 q_self, z=1 k, z=2 v, z=3 q_other -> qo.
// Every block is ONE pass -> 2048 equal blocks pack into 6/CU residency in
// ~1.33 rounds (vs 2.0 with the double-pass q slice). attn sums qc+qo.
__global__ __launch_bounds__(256) void gemm_proj4(
    const unsigned short* __restrict__ xb, const unsigned short* __restrict__ qb,
    const float* __restrict__ Wqs, const float* __restrict__ Wqo,
    const float* __restrict__ Wk, const float* __restrict__ Wv,
    unsigned short* __restrict__ qc, unsigned short* __restrict__ qo,
    unsigned short* __restrict__ kk, unsigned short* __restrict__ vt)
{
    __shared__ alignas(16) unsigned short As[128 * 64];
    __shared__ alignas(16) unsigned short Bs[64 * 64];
    floatx4 acc[4][2] = {};
    int bx, by; remap8(bx, by);
    const int mblk = by * 128, nblk = bx * 64;
    if (blockIdx.z == 0) {
        gemm_pass(xb, Wqs, mblk, nblk, 0, 16, As, Bs, acc);
        store_nat(acc, As, qc, mblk, nblk);
    } else if (blockIdx.z == 1) {
        gemm_pass(xb, Wk, mblk, nblk, 0, 16, As, Bs, acc);
        store_nat(acc, As, kk, mblk, nblk);
    } else if (blockIdx.z == 2) {
        gemm_pass(xb, Wv, mblk, nblk, 0, 16, As, Bs, acc);
        store_vt(acc, As, vt, mblk, bx);
    } else {
        gemm_pass(qb, Wqo, mblk, nblk, 0, 16, As, Bs, acc);
        store_nat(acc, As, qo, mblk, nblk);
    }
}

// Round-6 fused q/k/v (q = two passes); used when 24 <= ws < 32 MiB.
__global__ __launch_bounds__(256) void gemm_proj3(
    const unsigned short* __restrict__ xb, const unsigned short* __restrict__ qb,
    const float* __restrict__ Wqs, const float* __restrict__ Wqo,
    const float* __restrict__ Wk, const float* __restrict__ Wv,
    unsigned short* __restrict__ qc, unsigned short* __restrict__ kk,
    unsigned short* __restrict__ vt)
{
    __shared__ alignas(16) unsigned short As[128 * 64];
    __shared__ alignas(16) unsigned short Bs[64 * 64];
    floatx4 acc[4][2] = {};
    int bx, by; remap8(bx, by);
    const int mblk = by * 128, nblk = bx * 64;
    if (blockIdx.z == 0) {
        gemm_pass(xb, Wqs, mblk, nblk, 0, 16, As, Bs, acc);
        gemm_pass(qb, Wqo, mblk, nblk, 0, 16, As, Bs, acc);
        store_nat(acc, As, qc, mblk, nblk);
    } else if (blockIdx.z == 1) {
        gemm_pass(xb, Wk, mblk, nblk, 0, 16, As, Bs, acc);
        store_nat(acc, As, kk, mblk, nblk);
    } else {
        gemm_pass(xb, Wv, mblk, nblk, 0, 16, As, Bs, acc);
        store_vt(acc, As, vt, mblk, bx);
    }
}

// Lean path (vt aliases qb): q+k fused first, v alone after q consumed qb.
__global__ __launch_bounds__(256) void gemm_projqk(
    const unsigned short* __restrict__ xb, const unsigned short* __restrict__ qb,
    const float* __restrict__ Wqs, const float* __restrict__ Wqo,
    const float* __restrict__ Wk,
    unsigned short* __restrict__ qc, unsigned short* __restrict__ kk)
{
    __shared__ alignas(16) unsigned short As[128 * 64];
    __shared__ alignas(16) unsigned short Bs[64 * 64];
    floatx4 acc[4][2] = {};
    int bx, by; remap8(bx, by);
    const int mblk = by * 128, nblk = bx * 64;
    if (blockIdx.z == 0) {
        gemm_pass(xb, Wqs, mblk, nblk, 0, 16, As, Bs, acc);
        gemm_pass(qb, Wqo, mblk, nblk, 0, 16, As, Bs, acc);
        store_nat(acc, As, qc, mblk, nblk);
    } else {
        gemm_pass(xb, Wk, mblk, nblk, 0, 16, As, Bs, acc);
        store_nat(acc, As, kk, mblk, nblk);
    }
}

__global__ __launch_bounds__(256) void gemm_v(
    const unsigned short* __restrict__ xb, const float* __restrict__ Wv,
    unsigned short* __restrict__ vt)
{
    __shared__ alignas(16) unsigned short As[128 * 64];
    __shared__ alignas(16) unsigned short Bs[64 * 64];
    floatx4 acc[4][2] = {};
    int bx, by; remap8(bx, by);
    gemm_pass(xb, Wv, by * 128, bx * 64, 0, 16, As, Bs, acc);
    store_vt(acc, As, vt, by * 128, bx);
}

// Wo projection, split-K x2: z = K-half, bf16 partials to pj0/pj1 (summed in ln).
// grid (16, 32, 2) = 1024 blocks -> 4/CU.
__global__ __launch_bounds__(256) void gemm_wo(
    const unsigned short* __restrict__ ao, const float* __restrict__ Wo,
    unsigned short* __restrict__ pj0, unsigned short* __restrict__ pj1)
{
    __shared__ alignas(16) unsigned short As[128 * 64];
    __shared__ alignas(16) unsigned short Bs[64 * 64];
    floatx4 acc[4][2] = {};
    int bx, by; remap8(bx, by);
    const int z = blockIdx.z;
    gemm_pass(ao, Wo, by * 128, bx * 64, z * 512, 8, As, Bs, acc);
    store_nat(acc, As, z ? pj1 : pj0, by * 128, bx * 64);
}

// ---------------------------------------------------------------------------
// Flash attention, swapped-QK^T in-register softmax (no online max: scores
// bounded, masked cols underflow to 0 via MBIAS add). mfma(K,Q) makes the
// P-row lane-local -> P->bf16 via cvt_pk + 16 shfl. K/V double-buffered in
// LDS, ONE barrier per iteration, loads 2 tiles deep. LDS 36KB -> 4/CU.
// SUMQ: Q = qc + qo (balanced projection path).
// ---------------------------------------------------------------------------
__device__ __forceinline__ int swzb(int row, int slot) {
    return (row << 7) + ((slot ^ (row & 7)) << 4);
}

template <int SUMQ>
__global__ __launch_bounds__(256, 4) void attn_flash(const unsigned short* qc,
                                                     const unsigned short* qo,
                                                     const unsigned short* __restrict__ kmat,
                                                     const unsigned short* __restrict__ vt,
                                                     const int* __restrict__ mask,
                                                     unsigned short* ao)
{
    const int blk = blockIdx.x;
    const int xcd = blk & 7;
    const int sub = blk >> 3;          // 0..127
    const int bh  = xcd * 8 + (sub >> 4);
    const int qt  = sub & 15;
    const int b   = bh >> 4;
    const int h   = bh & 15;

    const int wave = threadIdx.x >> 6;
    const int lane = threadIdx.x & 63;
    const int l16  = lane & 15;
    const int quad = lane >> 4;
    const int q0 = qt * 64 + wave * 16;

    __shared__ alignas(16) unsigned short Ks[2][64 * 64]; // swizzled [k][dh] 16KB
    __shared__ alignas(16) unsigned short Vs[2][64 * 64]; // swizzled [dh][k] 16KB
    __shared__ float Ml[LL];                              // mask bias         4KB

    const int* bm = mask + b * LL;
    for (int i = 0; i < 4; ++i) {
        const int c = threadIdx.x + i * 256;
        Ml[c] = (1.0f - (float)bm[c]) * MBIAS;
    }

    short8 aq[2];
    for (int s = 0; s < 2; ++s) {
        const size_t off = (size_t)(b * LL + q0 + l16) * AA + h * DHH + s * 32 + quad * 8;
        short8 t = *reinterpret_cast<const short8*>(qc + off);
        if (SUMQ) {
            short8 t1 = *reinterpret_cast<const short8*>(qo + off);
            for (int e = 0; e < 8; ++e)
                t[e] = (short)f2bf((bf2f((unsigned short)t[e]) +
                                    bf2f((unsigned short)t1[e])) * QSC);
        } else {
            for (int e = 0; e < 8; ++e)
                t[e] = (short)f2bf(bf2f((unsigned short)t[e]) * QSC);
        }
        aq[s] = t;
    }

    floatx4 O[4] = {};
    float lp = 0.f;

    const unsigned short* kbase = kmat + (size_t)(b * LL) * AA + h * DHH;
    const unsigned short* vbase = vt + (size_t)((b * HH + h) * DHH) * LL;
    const int c0 = threadIdx.x, c1 = threadIdx.x + 256;
    const int row0 = c0 >> 3, slot0 = c0 & 7;   // rows 0..31
    const int row1 = c1 >> 3, slot1 = c1 & 7;   // rows 32..63

    uint4 kr0, kr1, vr0, vr1;
    kr0 = *reinterpret_cast<const uint4*>(kbase + (size_t)row0 * AA + slot0 * 8);
    kr1 = *reinterpret_cast<const uint4*>(kbase + (size_t)row1 * AA + slot1 * 8);
    vr0 = *reinterpret_cast<const uint4*>(vbase + (size_t)row0 * LL + slot0 * 8);
    vr1 = *reinterpret_cast<const uint4*>(vbase + (size_t)row1 * LL + slot1 * 8);
    *reinterpret_cast<uint4*>((char*)Ks[0] + swzb(row0, slot0)) = kr0;
    *reinterpret_cast<uint4*>((char*)Ks[0] + swzb(row1, slot1)) = kr1;
    *reinterpret_cast<uint4*>((char*)Vs[0] + swzb(row0, slot0)) = vr0;
    *reinterpret_cast<uint4*>((char*)Vs[0] + swzb(row1, slot1)) = vr1;
    {
        const unsigned short* kb1 = kbase + (size_t)64 * AA;
        const unsigned short* vb1 = vbase + 64;
        kr0 = *reinterpret_cast<const uint4*>(kb1 + (size_t)row0 * AA + slot0 * 8);
        kr1 = *reinterpret_cast<const uint4*>(kb1 + (size_t)row1 * AA + slot1 * 8);
        vr0 = *reinterpret_cast<const uint4*>(vb1 + (size_t)row0 * LL + slot0 * 8);
        vr1 = *reinterpret_cast<const uint4*>(vb1 + (size_t)row1 * LL + slot1 * 8);
    }
    __syncthreads();

    const int srcA = ((quad & 1) << 5) + l16;   // source lanes for P redistribute
    const int srcB = srcA + 16;
    const bool hi = quad >= 2;                  // target j = quad>>1 selector
    int cur = 0;

    for (int t = 0; t < 16; ++t) {
        const char* Kc = (const char*)Ks[cur];
        const char* Vc = (const char*)Vs[cur];
        if (t + 1 < 16) {
            char* Kn = (char*)Ks[cur ^ 1];
            char* Vn = (char*)Vs[cur ^ 1];
            *reinterpret_cast<uint4*>(Kn + swzb(row0, slot0)) = kr0;
            *reinterpret_cast<uint4*>(Kn + swzb(row1, slot1)) = kr1;
            *reinterpret_cast<uint4*>(Vn + swzb(row0, slot0)) = vr0;
            *reinterpret_cast<uint4*>(Vn + swzb(row1, slot1)) = vr1;
        }
        if (t + 2 < 16) {
            const unsigned short* kb2 = kbase + (size_t)(t + 2) * 64 * AA;
            const unsigned short* vb2 = vbase + (t + 2) * 64;
            kr0 = *reinterpret_cast<const uint4*>(kb2 + (size_t)row0 * AA + slot0 * 8);
            kr1 = *reinterpret_cast<const uint4*>(kb2 + (size_t)row1 * AA + slot1 * 8);
            vr0 = *reinterpret_cast<const uint4*>(vb2 + (size_t)row0 * LL + slot0 * 8);
            vr1 = *reinterpret_cast<const uint4*>(vb2 + (size_t)row1 * LL + slot1 * 8);
        }

        floatx4 p[4];
        const float* Mlb = Ml + t * 64 + quad * 4;
        for (int j = 0; j < 4; ++j) {
            const int rr = j * 16 + l16;
            const short8 kf0 = *reinterpret_cast<const short8*>(Kc + swzb(rr, quad));
            const short8 kf1 = *reinterpret_cast<const short8*>(Kc + swzb(rr, quad + 4));
            floatx4 s_ = {0.f, 0.f, 0.f, 0.f};
            s_ = __builtin_amdgcn_mfma_f32_16x16x32_bf16(kf0, aq[0], s_, 0, 0, 0);
            s_ = __builtin_amdgcn_mfma_f32_16x16x32_bf16(kf1, aq[1], s_, 0, 0, 0);
            const float4 mv = *reinterpret_cast<const float4*>(Mlb + j * 16);
            p[j][0] = exp2f(s_[0] + mv.x);
            p[j][1] = exp2f(s_[1] + mv.y);
            p[j][2] = exp2f(s_[2] + mv.z);
            p[j][3] = exp2f(s_[3] + mv.w);
            lp += (p[j][0] + p[j][1]) + (p[j][2] + p[j][3]);
        }
        unsigned pk[4][2];
        for (int j = 0; j < 4; ++j) {
            pk[j][0] = pkbf(p[j][0], p[j][1]);
            pk[j][1] = pkbf(p[j][2], p[j][3]);
        }
        union { unsigned u[4]; short8 s; } ap0, ap1;
        {
            unsigned xA0 = __shfl((int)pk[0][0], srcA), yA0 = __shfl((int)pk[1][0], srcA);
            unsigned xA1 = __shfl((int)pk[0][1], srcA), yA1 = __shfl((int)pk[1][1], srcA);
            unsigned xB0 = __shfl((int)pk[0][0], srcB), yB0 = __shfl((int)pk[1][0], srcB);
            unsigned xB1 = __shfl((int)pk[0][1], srcB), yB1 = __shfl((int)pk[1][1], srcB);
            ap0.u[0] = hi ? yA0 : xA0;
            ap0.u[1] = hi ? yA1 : xA1;
            ap0.u[2] = hi ? yB0 : xB0;
            ap0.u[3] = hi ? yB1 : xB1;
        }
        {
            unsigned xA0 = __shfl((int)pk[2][0], srcA), yA0 = __shfl((int)pk[3][0], srcA);
            unsigned xA1 = __shfl((int)pk[2][1], srcA), yA1 = __shfl((int)pk[3][1], srcA);
            unsigned xB0 = __shfl((int)pk[2][0], srcB), yB0 = __shfl((int)pk[3][0], srcB);
            unsigned xB1 = __shfl((int)pk[2][1], srcB), yB1 = __shfl((int)pk[3][1], srcB);
            ap1.u[0] = hi ? yA0 : xA0;
            ap1.u[1] = hi ? yA1 : xA1;
            ap1.u[2] = hi ? yB0 : xB0;
            ap1.u[3] = hi ? yB1 : xB1;
        }
        for (int t4 = 0; t4 < 4; ++t4) {
            const int rr = t4 * 16 + l16;
            const short8 bv0 = *reinterpret_cast<const short8*>(Vc + swzb(rr, quad));
            const short8 bv1 = *reinterpret_cast<const short8*>(Vc + swzb(rr, quad + 4));
            O[t4] = __builtin_amdgcn_mfma_f32_16x16x32_bf16(ap0.s, bv0, O[t4], 0, 0, 0);
            O[t4] = __builtin_amdgcn_mfma_f32_16x16x32_bf16(ap1.s, bv1, O[t4], 0, 0, 0);
        }
        __syncthreads();
        cur ^= 1;
    }

    lp += __shfl_xor(lp, 16);
    lp += __shfl_xor(lp, 32);
    float linv[4];
    for (int r = 0; r < 4; ++r) {
        const float s = __shfl(lp, quad * 4 + r);
        linv[r] = 1.0f / s;
    }
    for (int t4 = 0; t4 < 4; ++t4)
        for (int r = 0; r < 4; ++r)
            ao[(size_t)(b * LL + q0 + quad * 4 + r) * AA + h * DHH + t4 * 16 + l16] =
                f2bf(O[t4][r] * linv[r]);
}

// bias + LayerNorm per 1024-row. Sums two bf16 partials; params fp32; out FP32.
__global__ __launch_bounds__(256) void ln_f32(const unsigned short* __restrict__ X0,
                                              const unsigned short* __restrict__ X1,
                                              const float* __restrict__ bo,
                                              const float* __restrict__ gamma,
                                              const float* __restrict__ beta,
                                              float* __restrict__ out)
{
    const int row = blockIdx.x;
    const unsigned short* x0 = X0 + (size_t)row * AA;
    const unsigned short* x1 = X1 + (size_t)row * AA;
    float v[4];
    float s = 0.f, s2 = 0.f;
    for (int e = 0; e < 4; ++e) {
        const int c = threadIdx.x + e * 256;
        const float f = bf2f(x0[c]) + bf2f(x1[c]) + bo[c];
        v[e] = f; s += f; s2 += f * f;
    }
    for (int d = 1; d < 64; d <<= 1) { s += __shfl_xor(s, d); s2 += __shfl_xor(s2, d); }
    __shared__ float red[4][2];
    const int wave = threadIdx.x >> 6;
    const int lane = threadIdx.x & 63;
    if (lane == 0) { red[wave][0] = s; red[wave][1] = s2; }
    __syncthreads();
    s  = red[0][0] + red[1][0] + red[2][0] + red[3][0];
    s2 = red[0][1] + red[1][1] + red[2][1] + red[3][1];
    const float mean = s * (1.0f / AA);
    const float var  = s2 * (1.0f / AA) - mean * mean;
    const float rstd = rsqrtf(var + 1e-5f);
    for (int e = 0; e < 4; ++e) {
        const int c = threadIdx.x + e * 256;
        out[(size_t)row * AA + c] = (v[e] - mean) * rstd * gamma[c] + beta[c];
    }
}

extern "C" void kernel_launch(void* const* d_in, const int* in_sizes, int n_in,
                              void* d_out, int out_size, void* d_ws, size_t ws_size,
                              hipStream_t stream)
{
    const float* x     = (const float*)d_in[0];  // fp32 [B][L][D]
    const float* qrs   = (const float*)d_in[1];
    const float* Wk    = (const float*)d_in[2];  // fp32 [A][D]
    const float* Wqs   = (const float*)d_in[3];
    const float* Wqo   = (const float*)d_in[4];
    const float* Wv    = (const float*)d_in[5];
    const float* Wo    = (const float*)d_in[6];
    const float* bo    = (const float*)d_in[7];
    const float* gamma = (const float*)d_in[8];
    const float* beta  = (const float*)d_in[9];
    const int*   mask  = (const int*)d_in[10];

    // Scratch plan (weights stay fp32, B-side reg-converted):
    //   ws[0,8):    xb (dead after projections) -> then pj0 (Wo K-half 0)
    //   ws[8,16):   qb (dead after q-pass)      -> then vt (lean path)
    //   ws[16,24):  vt (ws >= 24 MiB)
    //   ws[24,32):  qo (q_other partial, ws >= 32 MiB -> balanced 4-slice proj)
    //   d_out[0,8): qc (attn overwrites own region with ao)
    //   d_out[8,16): kk (dead after attn)       -> then pj1 (Wo K-half 1)
    //   d_out[0,16): final fp32 (written last by ln)
    char* ws = (char*)d_ws;
    unsigned short* xb = (unsigned short*)(ws + (size_t)0);
    unsigned short* qb = (unsigned short*)(ws + ((size_t)8 << 20));
    const bool big  = ws_size >= ((size_t)24 << 20);
    const bool ws32 = ws_size >= ((size_t)32 << 20);
    unsigned short* vt = big ? (unsigned short*)(ws + ((size_t)16 << 20)) : qb;
    unsigned short* qo = (unsigned short*)(ws + ((size_t)24 << 20));
    unsigned short* qc = (unsigned short*)d_out;
    unsigned short* kk = (unsigned short*)((char*)d_out + ((size_t)8 << 20));
    unsigned short* ao  = qc;
    unsigned short* pj0 = xb;
    unsigned short* pj1 = kk;

    ConvDesc cd;
    for (int i = 0; i < 4; ++i) {
        cd.s[i]     = x   + (size_t)i * (1u << 20); cd.d[i]     = xb + (size_t)i * (1u << 20);
        cd.s[i + 4] = qrs + (size_t)i * (1u << 20); cd.d[i + 4] = qb + (size_t)i * (1u << 20);
    }
    conv_f2b<<<8 * 1024, 256, 0, stream>>>(cd);

    if (ws32) {
        dim3 g4(AA / 64, (BB * LL) / 128, 4);
        gemm_proj4<<<g4, 256, 0, stream>>>(xb, qb, Wqs, Wqo, Wk, Wv, qc, qo, kk, vt);
        attn_flash<1><<<BB * HH * (LL / 64), 256, 0, stream>>>(qc, qo, kk, vt, mask, ao);
    } else if (big) {
        dim3 g3(AA / 64, (BB * LL) / 128, 3);
        gemm_proj3<<<g3, 256, 0, stream>>>(xb, qb, Wqs, Wqo, Wk, Wv, qc, kk, vt);
        attn_flash<0><<<BB * HH * (LL / 64), 256, 0, stream>>>(qc, qc, kk, vt, mask, ao);
    } else {
        dim3 g2(AA / 64, (BB * LL) / 128, 2);
        dim3 g1(AA / 64, (BB * LL) / 128);
        gemm_projqk<<<g2, 256, 0, stream>>>(xb, qb, Wqs, Wqo, Wk, qc, kk);
        gemm_v<<<g1, 256, 0, stream>>>(xb, Wv, vt);
        attn_flash<0><<<BB * HH * (LL / 64), 256, 0, stream>>>(qc, qc, kk, vt, mask, ao);
    }
    dim3 gw(AA / 64, (BB * LL) / 128, 2);
    gemm_wo<<<gw, 256, 0, stream>>>(ao, Wo, pj0, pj1);
    ln_f32<<<BB * LL, 256, 0, stream>>>(pj0, pj1, bo, gamma, beta, (float*)d_out);
}

// Round 9
// 217.814 us; speedup vs baseline: 1.1048x; 1.0795x over previous
//
#include <hip/hip_runtime.h>
#include <hip/hip_bf16.h>
#include <math.h>

// Problem constants (B=4, L=1024, D=A=1024, H=16, DH=64)
#define BB 4
#define LL 1024
#define DD 1024
#define AA 1024
#define HH 16
#define DHH 64
#define LOG2E 1.44269504f
#define QSC 0.045084223f        /* (1/32) * log2(e) */
#define MBIAS -144269.5f        /* -100000 * log2(e) */

typedef __attribute__((ext_vector_type(8))) short short8;
typedef __attribute__((ext_vector_type(4))) float floatx4;

__device__ __forceinline__ float bf2f(unsigned short u) {
    union { unsigned u; float f; } x; x.u = ((unsigned)u) << 16; return x.f;
}
__device__ __forceinline__ unsigned short f2bf(float f) {
    union { float f; unsigned u; } x; x.f = f;
    unsigned r = x.u + 0x7fffu + ((x.u >> 16) & 1u); // RNE
    return (unsigned short)(r >> 16);
}
__device__ __forceinline__ unsigned pkbf(float a, float b) { // packed RNE pair
    union { __hip_bfloat162 h; unsigned u; } c;
    c.h = __float22bfloat162_rn(make_float2(a, b));
    return c.u;
}

// async global->LDS, 16B per lane. LDS dest = wave-uniform base + lane*16.
__device__ __forceinline__ void gload16(const void* g, const void* l) {
    __builtin_amdgcn_global_load_lds(
        (const __attribute__((address_space(1))) unsigned int*)g,
        (__attribute__((address_space(3))) unsigned int*)l, 16, 0, 0);
}

// Bijective XCD remap for 512-block (16x32) z-slices: lin&7 = XCD under
// round-robin dispatch; each XCD gets an 8y x 8x sub-grid so its unique
// working set fits the 4MB per-XCD L2. (512 % 8 == 0 keeps phase alignment.)
__device__ __forceinline__ void remap8(int& bx, int& by) {
    const int lin = blockIdx.x + (blockIdx.y << 4);
    const int xcd = lin & 7, f = lin >> 3;          // f in 0..63
    by = ((xcd >> 1) << 3) + (f >> 3);
    bx = ((xcd & 1) << 3) + (f & 7);
}

// ---------------------------------------------------------------------------
// fp32 -> bf16 bulk converter. Unit = 1M elems = 1024 blocks; block = 1024 elems.
// ---------------------------------------------------------------------------
struct ConvDesc { const float* s[12]; unsigned short* d[12]; };

__global__ __launch_bounds__(256) void conv_f2b(ConvDesc cd) {
    const int u  = blockIdx.x >> 10;
    const int lb = blockIdx.x & 1023;
    const int idx = lb * 1024 + threadIdx.x * 4;
    float4 v = *reinterpret_cast<const float4*>(cd.s[u] + idx);
    uint2 o;
    o.x = pkbf(v.x, v.y);
    o.y = pkbf(v.z, v.w);
    *reinterpret_cast<uint2*>(cd.d[u] + idx) = o;
}

// ---------------------------------------------------------------------------
// 128x64-tile GEMM pass, BK=64, 2-barrier loop (round-6 proven core; 6/CU).
//   A: bf16 via global_load_lds, source-col pre-swizzled (rule #21).
//   B: BBF ? bf16 via global_load_lds (2 issues, no VALU, no VGPR round-trip)
//          : fp32 reg-prefetched + converted at swizzled ds_write (fallback).
// Fragment reads: slot' = (kh*4+quad) ^ (row&7) -> conflict-free.
// 4 waves (2x2): wave computes 64x32 = 4x2 frags of 16x16.
// C[m][n] += sum_{k range} A[m][k]*B[n][k].
// ---------------------------------------------------------------------------
template <bool BBF>
__device__ __forceinline__ void gemm_pass(const unsigned short* A, const void* Bv,
                                          int mblk, int nblk,
                                          int kbase, int ksteps,
                                          unsigned short* As, unsigned short* Bs,
                                          floatx4 (&acc)[4][2])
{
    const int tid  = threadIdx.x;
    const int lane = tid & 63;
    const int l16  = lane & 15;
    const int quad = lane >> 4;
    const int wave = tid >> 6;
    const int wm = wave >> 1, wn = wave & 1;
    const int arow = wave * 8 + (lane >> 3);            // 0..31
    const int acol = ((lane & 7) ^ (lane >> 3)) << 3;   // pre-swizzled col
    const unsigned short* Bb = (const unsigned short*)Bv;
    const float* Bf = (const float*)Bv;
    // fp32-B staging constants
    const int brow = tid >> 3;
    const int bcol = (tid & 7) << 3;
    const int bslot = ((tid & 7) ^ (brow & 7)) << 3;

    float4 br[4];
    if (!BBF) {   // preload B step 0
        const float* p0 = Bf + (size_t)(nblk + brow) * DD + kbase + bcol;
        const float* p1 = Bf + (size_t)(nblk + brow + 32) * DD + kbase + bcol;
        br[0] = ((const float4*)p0)[0]; br[1] = ((const float4*)p0)[1];
        br[2] = ((const float4*)p1)[0]; br[3] = ((const float4*)p1)[1];
    }

    for (int s = 0; s < ksteps; ++s) {
        const int k0 = kbase + s * 64;
        __syncthreads();                      // prev compute done, LDS free
        for (int is = 0; is < 4; ++is)
            gload16(A + (size_t)(mblk + is * 32 + arow) * DD + k0 + acol,
                    As + is * 2048 + wave * 512);
        if (BBF) {
            for (int is = 0; is < 2; ++is)
                gload16(Bb + (size_t)(nblk + is * 32 + arow) * DD + k0 + acol,
                        Bs + is * 2048 + wave * 512);
        } else {
            uint4 t0, t1;
            t0.x = pkbf(br[0].x, br[0].y); t0.y = pkbf(br[0].z, br[0].w);
            t0.z = pkbf(br[1].x, br[1].y); t0.w = pkbf(br[1].z, br[1].w);
            t1.x = pkbf(br[2].x, br[2].y); t1.y = pkbf(br[2].z, br[2].w);
            t1.z = pkbf(br[3].x, br[3].y); t1.w = pkbf(br[3].z, br[3].w);
            *reinterpret_cast<uint4*>(Bs + brow * 64 + bslot) = t0;
            *reinterpret_cast<uint4*>(Bs + (brow + 32) * 64 + bslot) = t1;
        }
        __syncthreads();                      // vmcnt+lgkm drain by compiler
        if (!BBF && s + 1 < ksteps) {
            const int nk = k0 + 64;
            const float* p0 = Bf + (size_t)(nblk + brow) * DD + nk + bcol;
            const float* p1 = Bf + (size_t)(nblk + brow + 32) * DD + nk + bcol;
            br[0] = ((const float4*)p0)[0]; br[1] = ((const float4*)p0)[1];
            br[2] = ((const float4*)p1)[0]; br[3] = ((const float4*)p1)[1];
        }
        for (int kh = 0; kh < 2; ++kh) {
            const int sl = ((kh * 4 + quad) ^ (l16 & 7)) << 3;
            short8 af[4], bfr[2];
            for (int i = 0; i < 4; ++i)
                af[i] = *reinterpret_cast<const short8*>(
                    As + (wm * 64 + i * 16 + l16) * 64 + sl);
            for (int j = 0; j < 2; ++j)
                bfr[j] = *reinterpret_cast<const short8*>(
                    Bs + (wn * 32 + j * 16 + l16) * 64 + sl);
            for (int i = 0; i < 4; ++i)
                for (int j = 0; j < 2; ++j)
                    acc[i][j] = __builtin_amdgcn_mfma_f32_16x16x32_bf16(
                        af[i], bfr[j], acc[i][j], 0, 0, 0);
        }
    }
}

// Epilogue: acc -> per-wave LDS transpose -> full-line 16B coalesced stores.
__device__ __forceinline__ void store_nat(floatx4 (&acc)[4][2], unsigned short* As,
                                          unsigned short* C, int mblk, int nblk)
{
    const int lane = threadIdx.x & 63;
    const int l16  = lane & 15;
    const int quad = lane >> 4;
    const int wave = threadIdx.x >> 6;
    const int wm = wave >> 1, wn = wave & 1;
    __syncthreads();
    unsigned short* Cw = As + wave * 2048;        // [64][32] per wave
    for (int i = 0; i < 4; ++i)
        for (int j = 0; j < 2; ++j)
            for (int r = 0; r < 4; ++r)
                Cw[(i * 16 + quad * 4 + r) * 32 + j * 16 + l16] = f2bf(acc[i][j][r]);
    __asm__ volatile("s_waitcnt lgkmcnt(0)" ::: "memory");
    const int mb = mblk + wm * 64;
    const int nb = nblk + wn * 32;
    for (int s = 0; s < 4; ++s) {
        const int row = s * 16 + (lane >> 2);
        uint4 v = *reinterpret_cast<const uint4*>(Cw + row * 32 + (lane & 3) * 8);
        *reinterpret_cast<uint4*>(C + (size_t)(mb + row) * AA + nb + (lane & 3) * 8) = v;
    }
}

// V^T layout: vt[((b*H+h)*DH+dh)*L + l], wave region 32 dh x 64 l.
__device__ __forceinline__ void store_vt(floatx4 (&acc)[4][2], unsigned short* As,
                                         unsigned short* vt, int mblk, int h)
{
    const int lane = threadIdx.x & 63;
    const int l16  = lane & 15;
    const int quad = lane >> 4;
    const int wave = threadIdx.x >> 6;
    const int wm = wave >> 1, wn = wave & 1;
    __syncthreads();
    unsigned short* Cw = As + wave * 2048;        // [32 dh][64 l] per wave
    for (int i = 0; i < 4; ++i)
        for (int j = 0; j < 2; ++j) {
            ushort4 pv;
            pv.x = f2bf(acc[i][j][0]); pv.y = f2bf(acc[i][j][1]);
            pv.z = f2bf(acc[i][j][2]); pv.w = f2bf(acc[i][j][3]);
            *reinterpret_cast<ushort4*>(&Cw[(j * 16 + l16) * 64 + i * 16 + quad * 4]) = pv;
        }
    __asm__ volatile("s_waitcnt lgkmcnt(0)" ::: "memory");
    const int mg = mblk + wm * 64;
    const int b  = mg >> 10, lbase = mg & 1023;
    for (int s = 0; s < 4; ++s) {
        const int drow = s * 8 + (lane >> 3);     // 0..31
        uint4 v = *reinterpret_cast<const uint4*>(Cw + drow * 64 + (lane & 7) * 8);
        *reinterpret_cast<uint4*>(
            vt + (size_t)((b * HH + h) * DHH + wn * 32 + drow) * LL + lbase + (lane & 7) * 8) = v;
    }
}

// Fused q/k/v projections (q = two passes). BBF: weights bf16 (pre-converted).
template <bool BBF>
__global__ __launch_bounds__(256) void gemm_proj3(
    const unsigned short* __restrict__ xb, const unsigned short* __restrict__ qb,
    const void* __restrict__ Wqs, const void* __restrict__ Wqo,
    const void* __restrict__ Wk, const void* __restrict__ Wv,
    unsigned short* __restrict__ qc, unsigned short* __restrict__ kk,
    unsigned short* __restrict__ vt)
{
    __shared__ alignas(16) unsigned short As[128 * 64];
    __shared__ alignas(16) unsigned short Bs[64 * 64];
    floatx4 acc[4][2] = {};
    int bx, by; remap8(bx, by);
    const int mblk = by * 128, nblk = bx * 64;
    if (blockIdx.z == 0) {
        gemm_pass<BBF>(xb, Wqs, mblk, nblk, 0, 16, As, Bs, acc);
        gemm_pass<BBF>(qb, Wqo, mblk, nblk, 0, 16, As, Bs, acc);
        store_nat(acc, As, qc, mblk, nblk);
    } else if (blockIdx.z == 1) {
        gemm_pass<BBF>(xb, Wk, mblk, nblk, 0, 16, As, Bs, acc);
        store_nat(acc, As, kk, mblk, nblk);
    } else {
        gemm_pass<BBF>(xb, Wv, mblk, nblk, 0, 16, As, Bs, acc);
        store_vt(acc, As, vt, mblk, bx);
    }
}

// Lean path (vt aliases qb): q+k fused first, v alone after q consumed qb.
__global__ __launch_bounds__(256) void gemm_projqk(
    const unsigned short* __restrict__ xb, const unsigned short* __restrict__ qb,
    const float* __restrict__ Wqs, const float* __restrict__ Wqo,
    const float* __restrict__ Wk,
    unsigned short* __restrict__ qc, unsigned short* __restrict__ kk)
{
    __shared__ alignas(16) unsigned short As[128 * 64];
    __shared__ alignas(16) unsigned short Bs[64 * 64];
    floatx4 acc[4][2] = {};
    int bx, by; remap8(bx, by);
    const int mblk = by * 128, nblk = bx * 64;
    if (blockIdx.z == 0) {
        gemm_pass<false>(xb, Wqs, mblk, nblk, 0, 16, As, Bs, acc);
        gemm_pass<false>(qb, Wqo, mblk, nblk, 0, 16, As, Bs, acc);
        store_nat(acc, As, qc, mblk, nblk);
    } else {
        gemm_pass<false>(xb, Wk, mblk, nblk, 0, 16, As, Bs, acc);
        store_nat(acc, As, kk, mblk, nblk);
    }
}

__global__ __launch_bounds__(256) void gemm_v(
    const unsigned short* __restrict__ xb, const float* __restrict__ Wv,
    unsigned short* __restrict__ vt)
{
    __shared__ alignas(16) unsigned short As[128 * 64];
    __shared__ alignas(16) unsigned short Bs[64 * 64];
    floatx4 acc[4][2] = {};
    int bx, by; remap8(bx, by);
    gemm_pass<false>(xb, Wv, by * 128, bx * 64, 0, 16, As, Bs, acc);
    store_vt(acc, As, vt, by * 128, bx);
}

// Wo projection, split-K x2: z = K-half, bf16 partials to pj0/pj1 (summed in ln).
template <bool BBF>
__global__ __launch_bounds__(256) void gemm_wo(
    const unsigned short* __restrict__ ao, const void* __restrict__ Wo,
    unsigned short* __restrict__ pj0, unsigned short* __restrict__ pj1)
{
    __shared__ alignas(16) unsigned short As[128 * 64];
    __shared__ alignas(16) unsigned short Bs[64 * 64];
    floatx4 acc[4][2] = {};
    int bx, by; remap8(bx, by);
    const int z = blockIdx.z;
    gemm_pass<BBF>(ao, Wo, by * 128, bx * 64, z * 512, 8, As, Bs, acc);
    store_nat(acc, As, z ? pj1 : pj0, by * 128, bx * 64);
}

// ---------------------------------------------------------------------------
// Flash attention, swapped-QK^T in-register softmax (no online max: scores
// bounded, masked cols underflow to 0 via MBIAS add). mfma(K,Q) makes the
// P-row lane-local -> P->bf16 via cvt_pk + 16 shfl. K/V double-buffered in
// LDS, ONE barrier per iteration, loads 2 tiles deep. LDS 36KB -> 4/CU.
// ---------------------------------------------------------------------------
__device__ __forceinline__ int swzb(int row, int slot) {
    return (row << 7) + ((slot ^ (row & 7)) << 4);
}

__global__ __launch_bounds__(256, 4) void attn_flash(const unsigned short* qc,
                                                     const unsigned short* __restrict__ kmat,
                                                     const unsigned short* __restrict__ vt,
                                                     const int* __restrict__ mask,
                                                     unsigned short* ao)
{
    const int blk = blockIdx.x;
    const int xcd = blk & 7;
    const int sub = blk >> 3;          // 0..127
    const int bh  = xcd * 8 + (sub >> 4);
    const int qt  = sub & 15;
    const int b   = bh >> 4;
    const int h   = bh & 15;

    const int wave = threadIdx.x >> 6;
    const int lane = threadIdx.x & 63;
    const int l16  = lane & 15;
    const int quad = lane >> 4;
    const int q0 = qt * 64 + wave * 16;

    __shared__ alignas(16) unsigned short Ks[2][64 * 64]; // swizzled [k][dh] 16KB
    __shared__ alignas(16) unsigned short Vs[2][64 * 64]; // swizzled [dh][k] 16KB
    __shared__ float Ml[LL];                              // mask bias         4KB

    const int* bm = mask + b * LL;
    for (int i = 0; i < 4; ++i) {
        const int c = threadIdx.x + i * 256;
        Ml[c] = (1.0f - (float)bm[c]) * MBIAS;
    }

    short8 aq[2];
    for (int s = 0; s < 2; ++s) {
        const unsigned short* p =
            qc + (size_t)(b * LL + q0 + l16) * AA + h * DHH + s * 32 + quad * 8;
        short8 t = *reinterpret_cast<const short8*>(p);
        for (int e = 0; e < 8; ++e)
            t[e] = (short)f2bf(bf2f((unsigned short)t[e]) * QSC);
        aq[s] = t;
    }

    floatx4 O[4] = {};
    float lp = 0.f;

    const unsigned short* kbase = kmat + (size_t)(b * LL) * AA + h * DHH;
    const unsigned short* vbase = vt + (size_t)((b * HH + h) * DHH) * LL;
    const int c0 = threadIdx.x, c1 = threadIdx.x + 256;
    const int row0 = c0 >> 3, slot0 = c0 & 7;   // rows 0..31
    const int row1 = c1 >> 3, slot1 = c1 & 7;   // rows 32..63

    uint4 kr0, kr1, vr0, vr1;
    kr0 = *reinterpret_cast<const uint4*>(kbase + (size_t)row0 * AA + slot0 * 8);
    kr1 = *reinterpret_cast<const uint4*>(kbase + (size_t)row1 * AA + slot1 * 8);
    vr0 = *reinterpret_cast<const uint4*>(vbase + (size_t)row0 * LL + slot0 * 8);
    vr1 = *reinterpret_cast<const uint4*>(vbase + (size_t)row1 * LL + slot1 * 8);
    *reinterpret_cast<uint4*>((char*)Ks[0] + swzb(row0, slot0)) = kr0;
    *reinterpret_cast<uint4*>((char*)Ks[0] + swzb(row1, slot1)) = kr1;
    *reinterpret_cast<uint4*>((char*)Vs[0] + swzb(row0, slot0)) = vr0;
    *reinterpret_cast<uint4*>((char*)Vs[0] + swzb(row1, slot1)) = vr1;
    {
        const unsigned short* kb1 = kbase + (size_t)64 * AA;
        const unsigned short* vb1 = vbase + 64;
        kr0 = *reinterpret_cast<const uint4*>(kb1 + (size_t)row0 * AA + slot0 * 8);
        kr1 = *reinterpret_cast<const uint4*>(kb1 + (size_t)row1 * AA + slot1 * 8);
        vr0 = *reinterpret_cast<const uint4*>(vb1 + (size_t)row0 * LL + slot0 * 8);
        vr1 = *reinterpret_cast<const uint4*>(vb1 + (size_t)row1 * LL + slot1 * 8);
    }
    __syncthreads();

    const int srcA = ((quad & 1) << 5) + l16;   // source lanes for P redistribute
    const int srcB = srcA + 16;
    const bool hi = quad >= 2;                  // target j = quad>>1 selector
    int cur = 0;

    for (int t = 0; t < 16; ++t) {
        const char* Kc = (const char*)Ks[cur];
        const char* Vc = (const char*)Vs[cur];
        if (t + 1 < 16) {
            char* Kn = (char*)Ks[cur ^ 1];
            char* Vn = (char*)Vs[cur ^ 1];
            *reinterpret_cast<uint4*>(Kn + swzb(row0, slot0)) = kr0;
            *reinterpret_cast<uint4*>(Kn + swzb(row1, slot1)) = kr1;
            *reinterpret_cast<uint4*>(Vn + swzb(row0, slot0)) = vr0;
            *reinterpret_cast<uint4*>(Vn + swzb(row1, slot1)) = vr1;
        }
        if (t + 2 < 16) {
            const unsigned short* kb2 = kbase + (size_t)(t + 2) * 64 * AA;
            const unsigned short* vb2 = vbase + (t + 2) * 64;
            kr0 = *reinterpret_cast<const uint4*>(kb2 + (size_t)row0 * AA + slot0 * 8);
            kr1 = *reinterpret_cast<const uint4*>(kb2 + (size_t)row1 * AA + slot1 * 8);
            vr0 = *reinterpret_cast<const uint4*>(vb2 + (size_t)row0 * LL + slot0 * 8);
            vr1 = *reinterpret_cast<const uint4*>(vb2 + (size_t)row1 * LL + slot1 * 8);
        }

        floatx4 p[4];
        const float* Mlb = Ml + t * 64 + quad * 4;
        for (int j = 0; j < 4; ++j) {
            const int rr = j * 16 + l16;
            const short8 kf0 = *reinterpret_cast<const short8*>(Kc + swzb(rr, quad));
            const short8 kf1 = *reinterpret_cast<const short8*>(Kc + swzb(rr, quad + 4));
            floatx4 s_ = {0.f, 0.f, 0.f, 0.f};
            s_ = __builtin_amdgcn_mfma_f32_16x16x32_bf16(kf0, aq[0], s_, 0, 0, 0);
            s_ = __builtin_amdgcn_mfma_f32_16x16x32_bf16(kf1, aq[1], s_, 0, 0, 0);
            const float4 mv = *reinterpret_cast<const float4*>(Mlb + j * 16);
            p[j][0] = exp2f(s_[0] + mv.x);
            p[j][1] = exp2f(s_[1] + mv.y);
            p[j][2] = exp2f(s_[2] + mv.z);
            p[j][3] = exp2f(s_[3] + mv.w);
            lp += (p[j][0] + p[j][1]) + (p[j][2] + p[j][3]);
        }
        unsigned pk[4][2];
        for (int j = 0; j < 4; ++j) {
            pk[j][0] = pkbf(p[j][0], p[j][1]);
            pk[j][1] = pkbf(p[j][2], p[j][3]);
        }
        union { unsigned u[4]; short8 s; } ap0, ap1;
        {
            unsigned xA0 = __shfl((int)pk[0][0], srcA), yA0 = __shfl((int)pk[1][0], srcA);
            unsigned xA1 = __shfl((int)pk[0][1], srcA), yA1 = __shfl((int)pk[1][1], srcA);
            unsigned xB0 = __shfl((int)pk[0][0], srcB), yB0 = __shfl((int)pk[1][0], srcB);
            unsigned xB1 = __shfl((int)pk[0][1], srcB), yB1 = __shfl((int)pk[1][1], srcB);
            ap0.u[0] = hi ? yA0 : xA0;
            ap0.u[1] = hi ? yA1 : xA1;
            ap0.u[2] = hi ? yB0 : xB0;
            ap0.u[3] = hi ? yB1 : xB1;
        }
        {
            unsigned xA0 = __shfl((int)pk[2][0], srcA), yA0 = __shfl((int)pk[3][0], srcA);
            unsigned xA1 = __shfl((int)pk[2][1], srcA), yA1 = __shfl((int)pk[3][1], srcA);
            unsigned xB0 = __shfl((int)pk[2][0], srcB), yB0 = __shfl((int)pk[3][0], srcB);
            unsigned xB1 = __shfl((int)pk[2][1], srcB), yB1 = __shfl((int)pk[3][1], srcB);
            ap1.u[0] = hi ? yA0 : xA0;
            ap1.u[1] = hi ? yA1 : xA1;
            ap1.u[2] = hi ? yB0 : xB0;
            ap1.u[3] = hi ? yB1 : xB1;
        }
        for (int t4 = 0; t4 < 4; ++t4) {
            const int rr = t4 * 16 + l16;
            const short8 bv0 = *reinterpret_cast<const short8*>(Vc + swzb(rr, quad));
            const short8 bv1 = *reinterpret_cast<const short8*>(Vc + swzb(rr, quad + 4));
            O[t4] = __builtin_amdgcn_mfma_f32_16x16x32_bf16(ap0.s, bv0, O[t4], 0, 0, 0);
            O[t4] = __builtin_amdgcn_mfma_f32_16x16x32_bf16(ap1.s, bv1, O[t4], 0, 0, 0);
        }
        __syncthreads();
        cur ^= 1;
    }

    lp += __shfl_xor(lp, 16);
    lp += __shfl_xor(lp, 32);
    float linv[4];
    for (int r = 0; r < 4; ++r) {
        const float s = __shfl(lp, quad * 4 + r);
        linv[r] = 1.0f / s;
    }
    for (int t4 = 0; t4 < 4; ++t4)
        for (int r = 0; r < 4; ++r)
            ao[(size_t)(b * LL + q0 + quad * 4 + r) * AA + h * DHH + t4 * 16 + l16] =
                f2bf(O[t4][r] * linv[r]);
}

// bias + LayerNorm per 1024-row. Sums two bf16 partials; params fp32; out FP32.
__global__ __launch_bounds__(256) void ln_f32(const unsigned short* __restrict__ X0,
                                              const unsigned short* __restrict__ X1,
                                              const float* __restrict__ bo,
                                              const float* __restrict__ gamma,
                                              const float* __restrict__ beta,
                                              float* __restrict__ out)
{
    const int row = blockIdx.x;
    const unsigned short* x0 = X0 + (size_t)row * AA;
    const unsigned short* x1 = X1 + (size_t)row * AA;
    float v[4];
    float s = 0.f, s2 = 0.f;
    for (int e = 0; e < 4; ++e) {
        const int c = threadIdx.x + e * 256;
        const float f = bf2f(x0[c]) + bf2f(x1[c]) + bo[c];
        v[e] = f; s += f; s2 += f * f;
    }
    for (int d = 1; d < 64; d <<= 1) { s += __shfl_xor(s, d); s2 += __shfl_xor(s2, d); }
    __shared__ float red[4][2];
    const int wave = threadIdx.x >> 6;
    const int lane = threadIdx.x & 63;
    if (lane == 0) { red[wave][0] = s; red[wave][1] = s2; }
    __syncthreads();
    s  = red[0][0] + red[1][0] + red[2][0] + red[3][0];
    s2 = red[0][1] + red[1][1] + red[2][1] + red[3][1];
    const float mean = s * (1.0f / AA);
    const float var  = s2 * (1.0f / AA) - mean * mean;
    const float rstd = rsqrtf(var + 1e-5f);
    for (int e = 0; e < 4; ++e) {
        const int c = threadIdx.x + e * 256;
        out[(size_t)row * AA + c] = (v[e] - mean) * rstd * gamma[c] + beta[c];
    }
}

extern "C" void kernel_launch(void* const* d_in, const int* in_sizes, int n_in,
                              void* d_out, int out_size, void* d_ws, size_t ws_size,
                              hipStream_t stream)
{
    const float* x     = (const float*)d_in[0];  // fp32 [B][L][D]
    const float* qrs   = (const float*)d_in[1];
    const float* Wk    = (const float*)d_in[2];  // fp32 [A][D]
    const float* Wqs   = (const float*)d_in[3];
    const float* Wqo   = (const float*)d_in[4];
    const float* Wv    = (const float*)d_in[5];
    const float* Wo    = (const float*)d_in[6];
    const float* bo    = (const float*)d_in[7];
    const float* gamma = (const float*)d_in[8];
    const float* beta  = (const float*)d_in[9];
    const int*   mask  = (const int*)d_in[10];

    // Scratch plan, ws >= 32 MiB path (verified in r8 — gemm_proj4 ran):
    //   ws[0,8):    xb (dead after proj)  -> pj0 (Wo K-half 0)
    //   ws[8,16):   qb (dead after proj)  -> Wo_b (2MB, 2nd conv)
    //   ws[16,24):  vt (dead after attn)  -> pj1 (Wo K-half 1)
    //   ws[24,32):  Wqs_b,Wqo_b,Wk_b,Wv_b (2MB each; dead after proj)
    //   d_out[0,8): qc (attn overwrites own region with ao)
    //   d_out[8,16): kk (dead after attn)
    //   d_out[0,16): final fp32 (written last by ln)
    char* ws = (char*)d_ws;
    unsigned short* xb = (unsigned short*)(ws + (size_t)0);
    unsigned short* qb = (unsigned short*)(ws + ((size_t)8 << 20));
    const bool big  = ws_size >= ((size_t)24 << 20);
    const bool ws32 = ws_size >= ((size_t)32 << 20);
    unsigned short* vt = big ? (unsigned short*)(ws + ((size_t)16 << 20)) : qb;
    unsigned short* Wb = (unsigned short*)(ws + ((size_t)24 << 20));
    unsigned short* Wqs_b = Wb;
    unsigned short* Wqo_b = Wb + (1u << 20);
    unsigned short* Wk_b  = Wb + (2u << 20);
    unsigned short* Wv_b  = Wb + (3u << 20);
    unsigned short* Wo_b  = qb;                    // reuses qb after proj
    unsigned short* qc = (unsigned short*)d_out;
    unsigned short* kk = (unsigned short*)((char*)d_out + ((size_t)8 << 20));
    unsigned short* ao  = qc;
    unsigned short* pj0 = xb;
    unsigned short* pj1 = ws32 ? vt : kk;

    dim3 gp(AA / 64, (BB * LL) / 128, 3);
    dim3 gw(AA / 64, (BB * LL) / 128, 2);

    if (ws32) {
        ConvDesc cd;
        int nu = 0;
        for (int i = 0; i < 4; ++i) {
            cd.s[nu] = x   + (size_t)i * (1u << 20); cd.d[nu] = xb + (size_t)i * (1u << 20); ++nu;
            cd.s[nu] = qrs + (size_t)i * (1u << 20); cd.d[nu] = qb + (size_t)i * (1u << 20); ++nu;
        }
        cd.s[nu] = Wqs; cd.d[nu] = Wqs_b; ++nu;
        cd.s[nu] = Wqo; cd.d[nu] = Wqo_b; ++nu;
        cd.s[nu] = Wk;  cd.d[nu] = Wk_b;  ++nu;
        cd.s[nu] = Wv;  cd.d[nu] = Wv_b;  ++nu;
        conv_f2b<<<nu * 1024, 256, 0, stream>>>(cd);

        gemm_proj3<true><<<gp, 256, 0, stream>>>(xb, qb, Wqs_b, Wqo_b, Wk_b, Wv_b,
                                                 qc, kk, vt);
        ConvDesc cw;                               // Wo -> bf16 into dead qb
        cw.s[0] = Wo; cw.d[0] = Wo_b;
        conv_f2b<<<1024, 256, 0, stream>>>(cw);

        attn_flash<<<BB * HH * (LL / 64), 256, 0, stream>>>(qc, kk, vt, mask, ao);
        gemm_wo<true><<<gw, 256, 0, stream>>>(ao, Wo_b, pj0, pj1);
    } else {
        ConvDesc cd;
        for (int i = 0; i < 4; ++i) {
            cd.s[i]     = x   + (size_t)i * (1u << 20); cd.d[i]     = xb + (size_t)i * (1u << 20);
            cd.s[i + 4] = qrs + (size_t)i * (1u << 20); cd.d[i + 4] = qb + (size_t)i * (1u << 20);
        }
        conv_f2b<<<8 * 1024, 256, 0, stream>>>(cd);
        if (big) {
            gemm_proj3<false><<<gp, 256, 0, stream>>>(xb, qb, Wqs, Wqo, Wk, Wv,
                                                      qc, kk, vt);
        } else {
            dim3 g2(AA / 64, (BB * LL) / 128, 2);
            dim3 g1(AA / 64, (BB * LL) / 128);
            gemm_projqk<<<g2, 256, 0, stream>>>(xb, qb, Wqs, Wqo, Wk, qc, kk);
            gemm_v<<<g1, 256, 0, stream>>>(xb, Wv, vt);
        }
        attn_flash<<<BB * HH * (LL / 64), 256, 0, stream>>>(qc, kk, vt, mask, ao);
        gemm_wo<false><<<gw, 256, 0, stream>>>(ao, Wo, pj0, pj1);
    }
    ln_f32<<<BB * LL, 256, 0, stream>>>(pj0, pj1, bo, gamma, beta, (float*)d_out);
}